// Round 1
// 1104.145 us; speedup vs baseline: 6.2227x; 6.2227x over previous
//
#include <hip/hip_runtime.h>

#define B_ 2
#define S_ 2048
#define D_ 1024
#define H_ 16
#define HD_ 64
#define BH_ 32  // B_*H_

typedef float fx4 __attribute__((ext_vector_type(4)));
typedef short s16x8 __attribute__((ext_vector_type(8)));
typedef unsigned short u16x8 __attribute__((ext_vector_type(8)));
typedef unsigned short u16x4 __attribute__((ext_vector_type(4)));

#define MFMA16(a, b, c) __builtin_amdgcn_mfma_f32_16x16x32_bf16((a), (b), (c), 0, 0, 0)

__device__ __forceinline__ unsigned short f2bf(float x) {
    unsigned u = __float_as_uint(x);
    return (unsigned short)((u + 0x7FFFu + ((u >> 16) & 1u)) >> 16);  // RTNE
}
__device__ __forceinline__ float bf2f(unsigned short h) {
    return __uint_as_float(((unsigned)h) << 16);
}

// ---------------------------------------------------------------------------
// mask int32 -> bitmask (1 bit per element).  bit laneId of each u64 word.
__global__ __launch_bounds__(256) void mask_pack(const int* __restrict__ m,
                                                 unsigned long long* __restrict__ out) {
    size_t i = (size_t)blockIdx.x * 256 + threadIdx.x;
    unsigned long long b = __ballot(m[i] != 0);
    if ((threadIdx.x & 63) == 0) out[i >> 6] = b;
}

// ---------------------------------------------------------------------------
// out = X @ W^T + bias via split-bf16 MFMA (hi*hi + hi*lo + lo*hi ~ f32 accuracy).
// X:[4096][1024] f32, W:[1024][1024] f32 (both K-contiguous for A/B fragments).
// BM=128, BN=64, BK=64, 256 thr (4 waves as 2x2, wave tile 64x32).
// VMODE==0: write head-split bf16 hi/lo  out[(b*H+h)][s][hd]
// VMODE==1: write transposed bf16        vt[(b*H+h)][hd][s]
template <int VMODE>
__global__ __launch_bounds__(256) void proj_mfma(
    const float* __restrict__ X, const float* __restrict__ W, const float* __restrict__ bias,
    unsigned short* __restrict__ o_hi, unsigned short* __restrict__ o_lo) {
    // row stride 72 ushorts = 144 B (16B multiple -> aligned b128, 2-way banks = free)
    __shared__ __align__(16) unsigned short Ah[128 * 72];
    __shared__ __align__(16) unsigned short Al[128 * 72];
    __shared__ __align__(16) unsigned short Bh[64 * 72];
    __shared__ __align__(16) unsigned short Bl[64 * 72];

    const int t = threadIdx.x;
    const int n0 = blockIdx.x * 64;
    const int m0 = blockIdx.y * 128;
    const int wid = t >> 6, l = t & 63;
    const int wm = wid >> 1, wn = wid & 1;
    const int lr = l & 15, lq = l >> 4;

    fx4 acc[4][2];
#pragma unroll
    for (int i = 0; i < 4; ++i)
#pragma unroll
        for (int j = 0; j < 2; ++j) acc[i][j] = (fx4){0.f, 0.f, 0.f, 0.f};

    for (int k0 = 0; k0 < D_; k0 += 64) {
        // stage A tile 128x64 f32 -> hi/lo bf16 (fully coalesced float4 loads)
#pragma unroll
        for (int j = 0; j < 8; ++j) {
            int u = t + j * 256;                 // float4 unit 0..2047
            int row = u >> 4, c4 = (u & 15) * 4;
            float4 f = *(const float4*)(X + (size_t)(m0 + row) * D_ + k0 + c4);
            unsigned short h0 = f2bf(f.x), h1 = f2bf(f.y), h2 = f2bf(f.z), h3 = f2bf(f.w);
            u16x4 hv = {h0, h1, h2, h3};
            u16x4 lv = {f2bf(f.x - bf2f(h0)), f2bf(f.y - bf2f(h1)),
                        f2bf(f.z - bf2f(h2)), f2bf(f.w - bf2f(h3))};
            *(u16x4*)(Ah + row * 72 + c4) = hv;
            *(u16x4*)(Al + row * 72 + c4) = lv;
        }
        // stage B tile 64x64
#pragma unroll
        for (int j = 0; j < 4; ++j) {
            int u = t + j * 256;                 // 0..1023
            int row = u >> 4, c4 = (u & 15) * 4;
            float4 f = *(const float4*)(W + (size_t)(n0 + row) * D_ + k0 + c4);
            unsigned short h0 = f2bf(f.x), h1 = f2bf(f.y), h2 = f2bf(f.z), h3 = f2bf(f.w);
            u16x4 hv = {h0, h1, h2, h3};
            u16x4 lv = {f2bf(f.x - bf2f(h0)), f2bf(f.y - bf2f(h1)),
                        f2bf(f.z - bf2f(h2)), f2bf(f.w - bf2f(h3))};
            *(u16x4*)(Bh + row * 72 + c4) = hv;
            *(u16x4*)(Bl + row * 72 + c4) = lv;
        }
        __syncthreads();
#pragma unroll
        for (int c = 0; c < 2; ++c) {            // two K=32 chunks
            s16x8 a_h[4], a_l[4];
#pragma unroll
            for (int mf = 0; mf < 4; ++mf) {
                int ro = (wm * 64 + mf * 16 + lr) * 72 + c * 32 + lq * 8;
                a_h[mf] = *(const s16x8*)(Ah + ro);
                a_l[mf] = *(const s16x8*)(Al + ro);
            }
#pragma unroll
            for (int nf = 0; nf < 2; ++nf) {
                int ro = (wn * 32 + nf * 16 + lr) * 72 + c * 32 + lq * 8;
                s16x8 b_h = *(const s16x8*)(Bh + ro);
                s16x8 b_l = *(const s16x8*)(Bl + ro);
#pragma unroll
                for (int mf = 0; mf < 4; ++mf) {
                    acc[mf][nf] = MFMA16(a_h[mf], b_h, acc[mf][nf]);
                    acc[mf][nf] = MFMA16(a_h[mf], b_l, acc[mf][nf]);
                    acc[mf][nf] = MFMA16(a_l[mf], b_h, acc[mf][nf]);
                }
            }
        }
        __syncthreads();
    }

    if (VMODE == 0) {
        // D layout: col = lane&15 (n), row = (lane>>4)*4 + reg (m)
#pragma unroll
        for (int nf = 0; nf < 2; ++nf) {
            int n = n0 + wn * 32 + nf * 16 + lr;
            float bv = bias[n];
            int h = n >> 6, hd = n & 63;
#pragma unroll
            for (int mf = 0; mf < 4; ++mf)
#pragma unroll
                for (int r = 0; r < 4; ++r) {
                    int m = m0 + wm * 64 + mf * 16 + lq * 4 + r;
                    int b = m >> 11, s = m & 2047;
                    float v = acc[mf][nf][r] + bv;
                    size_t idx = ((size_t)((b * H_ + h) * S_ + s)) * HD_ + hd;
                    unsigned short hh = f2bf(v);
                    o_hi[idx] = hh;
                    o_lo[idx] = f2bf(v - bf2f(hh));
                }
        }
    } else {
        // transpose through LDS (reuse Ah), then coalesced bf16 writes of vt[bh][hd][s]
        unsigned short* T = Ah;  // 64 x 136 (stride 272B, 16B multiple)
#pragma unroll
        for (int nf = 0; nf < 2; ++nf) {
            int nl = wn * 32 + nf * 16 + lr;
            float bv = bias[n0 + nl];
#pragma unroll
            for (int mf = 0; mf < 4; ++mf)
#pragma unroll
                for (int r = 0; r < 4; ++r) {
                    int ml = wm * 64 + mf * 16 + lq * 4 + r;
                    T[nl * 136 + ml] = f2bf(acc[mf][nf][r] + bv);
                }
        }
        __syncthreads();
        int h = n0 >> 6, b = m0 >> 11, s0 = m0 & 2047;
        int hd = t >> 2, seg = t & 3;
        unsigned short* gp =
            o_hi + ((size_t)((b * H_ + h) * HD_ + hd)) * S_ + s0 + seg * 32;
#pragma unroll
        for (int j = 0; j < 4; ++j)
            *(u16x8*)(gp + j * 8) = *(const u16x8*)(T + hd * 136 + seg * 32 + j * 8);
    }
}

// ---------------------------------------------------------------------------
// Fused attention: 64 q-rows per block, 4 waves (16 rows each), K/V tiles of 64.
// Pass A: row-sums of exp(s) (single-bf16 scores; sum averages the rounding).
// Pass B: hi/lo-bf16 scores, write normalized attn (one pass), bf16-P PV MFMA.
// No max subtraction: scores ~ N(0,1); exp(s) safe in f32.  Masked -> e = 0.
__global__ __launch_bounds__(256) void attn_mfma(
    const unsigned short* __restrict__ qh_g, const unsigned short* __restrict__ ql_g,
    const unsigned short* __restrict__ kh_g, const unsigned short* __restrict__ kl_g,
    const unsigned short* __restrict__ vt_g, const unsigned long long* __restrict__ pm,
    float* __restrict__ ctx, float* __restrict__ attn) {
    __shared__ __align__(16) unsigned short Kh[64 * 72];
    __shared__ __align__(16) unsigned short Kl[64 * 72];
    __shared__ __align__(16) unsigned short VT[64 * 72];
    __shared__ __align__(16) float E[64 * 68];  // stride 272B: aligned b128, spread banks

    const int t = threadIdx.x;
    const int wid = t >> 6, l = t & 63, lr = l & 15, lq = l >> 4;
    const int q0 = blockIdx.x * 64;
    const int bh = blockIdx.y;
    const size_t base = (size_t)bh * S_ * HD_;
    const size_t mrow_base = (size_t)(bh & (B_ - 1)) * S_;  // faithful quirk: mask[bh % B]

    // Q fragments (A operand): row = q0 + wid*16 + (lane&15), k = (lane>>4)*8..+8
    s16x8 qhi[2], qlo[2];
    {
        const unsigned short* p = qh_g + base + (size_t)(q0 + wid * 16 + lr) * HD_ + lq * 8;
        qhi[0] = *(const s16x8*)p;
        qhi[1] = *(const s16x8*)(p + 32);
        const unsigned short* p2 = ql_g + base + (size_t)(q0 + wid * 16 + lr) * HD_ + lq * 8;
        qlo[0] = *(const s16x8*)p2;
        qlo[1] = *(const s16x8*)(p2 + 32);
    }

    float rs[4] = {0.f, 0.f, 0.f, 0.f};

    // ---------------- pass A: row sums of exp ----------------
    for (int kt = 0; kt < S_; kt += 64) {
#pragma unroll
        for (int j = 0; j < 2; ++j) {
            int u = t + j * 256;
            int row = u >> 3, c8 = (u & 7) * 8;
            *(u16x8*)(Kh + row * 72 + c8) =
                *(const u16x8*)(kh_g + base + (size_t)(kt + row) * HD_ + c8);
        }
        __syncthreads();
        fx4 acc[4];
#pragma unroll
        for (int nt = 0; nt < 4; ++nt) acc[nt] = (fx4){0.f, 0.f, 0.f, 0.f};
#pragma unroll
        for (int c = 0; c < 2; ++c)
#pragma unroll
            for (int nt = 0; nt < 4; ++nt) {
                s16x8 kb = *(const s16x8*)(Kh + (nt * 16 + lr) * 72 + c * 32 + lq * 8);
                acc[nt] = MFMA16(qhi[c], kb, acc[nt]);
            }
        unsigned long long mw[4];
#pragma unroll
        for (int r = 0; r < 4; ++r)
            mw[r] = pm[(mrow_base + q0 + wid * 16 + lq * 4 + r) * (S_ / 64) + (kt >> 6)];
#pragma unroll
        for (int nt = 0; nt < 4; ++nt)
#pragma unroll
            for (int r = 0; r < 4; ++r) {
                float e = __expf(acc[nt][r] * 0.125f);
                e = ((mw[r] >> (nt * 16 + lr)) & 1ull) ? 0.f : e;
                rs[r] += e;
            }
        __syncthreads();
    }
    // reduce row sums across the 16 col-lanes (contiguous 16-lane groups)
#pragma unroll
    for (int off = 1; off < 16; off <<= 1)
#pragma unroll
        for (int r = 0; r < 4; ++r) rs[r] += __shfl_xor(rs[r], off, 16);
    float inv[4];
#pragma unroll
    for (int r = 0; r < 4; ++r) inv[r] = 1.f / rs[r];

    // ---------------- pass B: normalized attn + PV ----------------
    fx4 pacc[4];
#pragma unroll
    for (int dt = 0; dt < 4; ++dt) pacc[dt] = (fx4){0.f, 0.f, 0.f, 0.f};

    for (int kt = 0; kt < S_; kt += 64) {
#pragma unroll
        for (int j = 0; j < 2; ++j) {
            int u = t + j * 256;
            int row = u >> 3, c8 = (u & 7) * 8;
            *(u16x8*)(Kh + row * 72 + c8) =
                *(const u16x8*)(kh_g + base + (size_t)(kt + row) * HD_ + c8);
            *(u16x8*)(Kl + row * 72 + c8) =
                *(const u16x8*)(kl_g + base + (size_t)(kt + row) * HD_ + c8);
            *(u16x8*)(VT + row * 72 + c8) =
                *(const u16x8*)(vt_g + (size_t)(bh * HD_ + row) * S_ + kt + c8);
        }
        __syncthreads();
        fx4 acc[4];
#pragma unroll
        for (int nt = 0; nt < 4; ++nt) acc[nt] = (fx4){0.f, 0.f, 0.f, 0.f};
#pragma unroll
        for (int c = 0; c < 2; ++c)
#pragma unroll
            for (int nt = 0; nt < 4; ++nt) {
                int ro = (nt * 16 + lr) * 72 + c * 32 + lq * 8;
                s16x8 kbh = *(const s16x8*)(Kh + ro);
                s16x8 kbl = *(const s16x8*)(Kl + ro);
                acc[nt] = MFMA16(qhi[c], kbh, acc[nt]);
                acc[nt] = MFMA16(qhi[c], kbl, acc[nt]);
                acc[nt] = MFMA16(qlo[c], kbh, acc[nt]);
            }
        unsigned long long mw[4];
#pragma unroll
        for (int r = 0; r < 4; ++r)
            mw[r] = pm[(mrow_base + q0 + wid * 16 + lq * 4 + r) * (S_ / 64) + (kt >> 6)];
#pragma unroll
        for (int nt = 0; nt < 4; ++nt)
#pragma unroll
            for (int r = 0; r < 4; ++r) {
                float e = __expf(acc[nt][r] * 0.125f);
                e = ((mw[r] >> (nt * 16 + lr)) & 1ull) ? 0.f : e;
                E[(wid * 16 + lq * 4 + r) * 68 + nt * 16 + lr] = e * inv[r];
            }
        __syncthreads();
        // PV: A = normalized P (rows wid*16+lr, cols c*32+lq*8), B = VT (rows = d)
#pragma unroll
        for (int c = 0; c < 2; ++c) {
            const float* ep = E + (wid * 16 + lr) * 68 + c * 32 + lq * 8;
            fx4 p0 = *(const fx4*)ep;
            fx4 p1 = *(const fx4*)(ep + 4);
            s16x8 pa;
#pragma unroll
            for (int i = 0; i < 4; ++i) {
                pa[i] = (short)f2bf(p0[i]);
                pa[i + 4] = (short)f2bf(p1[i]);
            }
#pragma unroll
            for (int dt = 0; dt < 4; ++dt) {
                s16x8 vb = *(const s16x8*)(VT + (dt * 16 + lr) * 72 + c * 32 + lq * 8);
                pacc[dt] = MFMA16(pa, vb, pacc[dt]);
            }
        }
        // coalesced attn write (each 4-lane cluster writes a contiguous 256B row chunk)
        {
            int rr = t >> 2, seg = t & 3;
            float* gout = attn + ((size_t)bh * S_ + q0 + rr) * S_ + kt + seg * 16;
            const float* ep2 = E + rr * 68 + seg * 16;
#pragma unroll
            for (int j = 0; j < 4; ++j) *(fx4*)(gout + j * 4) = *(const fx4*)(ep2 + j * 4);
        }
        __syncthreads();
    }

    // ctx epilogue: D layout row=(lane>>4)*4+reg (q), col=lane&15 (d)
    const int b = bh >> 4, h = bh & 15;
#pragma unroll
    for (int dt = 0; dt < 4; ++dt)
#pragma unroll
        for (int r = 0; r < 4; ++r) {
            int q = q0 + wid * 16 + lq * 4 + r;
            ctx[((size_t)(b * S_ + q)) * D_ + h * HD_ + dt * 16 + lr] = pacc[dt][r];
        }
}

// ---------------------------------------------------------------------------
extern "C" void kernel_launch(void* const* d_in, const int* in_sizes, int n_in,
                              void* d_out, int out_size, void* d_ws, size_t ws_size,
                              hipStream_t stream) {
    (void)in_sizes; (void)n_in; (void)out_size; (void)ws_size;
    const float* q_in = (const float*)d_in[0];
    const float* k_in = (const float*)d_in[1];
    const float* v_in = (const float*)d_in[2];
    const int* mask = (const int*)d_in[3];
    const float* Wq = (const float*)d_in[4];
    const float* bq = (const float*)d_in[5];
    const float* Wk = (const float*)d_in[6];
    const float* bk = (const float*)d_in[7];
    const float* Wv = (const float*)d_in[8];
    const float* bv = (const float*)d_in[9];

    const size_t E_ = (size_t)BH_ * S_ * HD_;  // 4,194,304 elements per array
    unsigned short* qh = (unsigned short*)d_ws;
    unsigned short* ql = qh + E_;
    unsigned short* kh = ql + E_;
    unsigned short* kl = kh + E_;
    unsigned short* vt = kl + E_;
    unsigned long long* pmask = (unsigned long long*)(vt + E_);
    // total ws: 5*8MB bf16 + 1MB bitmask = 43MB (previous kernel used 50MB: fits)

    float* ctx = (float*)d_out;
    float* attn = ctx + (size_t)B_ * S_ * D_;

    mask_pack<<<dim3((B_ * S_ * S_) / 256), dim3(256), 0, stream>>>(mask, pmask);

    dim3 pgrid(D_ / 64, (B_ * S_) / 128);  // (16, 32)
    proj_mfma<0><<<pgrid, dim3(256), 0, stream>>>(q_in, Wq, bq, qh, ql);
    proj_mfma<0><<<pgrid, dim3(256), 0, stream>>>(k_in, Wk, bk, kh, kl);
    proj_mfma<1><<<pgrid, dim3(256), 0, stream>>>(v_in, Wv, bv, vt, nullptr);

    dim3 agrid(S_ / 64, BH_);  // (32, 32)
    attn_mfma<<<agrid, dim3(256), 0, stream>>>(qh, ql, kh, kl, vt, pmask, ctx, attn);
}

// Round 2
// 1004.273 us; speedup vs baseline: 6.8416x; 1.0994x over previous
//
#include <hip/hip_runtime.h>

#define B_ 2
#define S_ 2048
#define D_ 1024
#define H_ 16
#define HD_ 64
#define BH_ 32  // B_*H_

typedef float fx4 __attribute__((ext_vector_type(4)));
typedef short s16x8 __attribute__((ext_vector_type(8)));
typedef unsigned short u16x8 __attribute__((ext_vector_type(8)));
typedef unsigned short u16x4 __attribute__((ext_vector_type(4)));

typedef __attribute__((address_space(1))) unsigned int uint_as1;
typedef __attribute__((address_space(3))) unsigned int uint_as3;

#define MFMA16(a, b, c) __builtin_amdgcn_mfma_f32_16x16x32_bf16((a), (b), (c), 0, 0, 0)

// Q (and bq) pre-scaled by 0.125 * log2(e) so score epilogue is a bare exp2.
#define QSCALE 0.18033688011112042f

#if __has_builtin(__builtin_amdgcn_exp2f)
#define EXP2F(x) __builtin_amdgcn_exp2f(x)
#else
#define EXP2F(x) exp2f(x)
#endif

__device__ __forceinline__ unsigned short f2bf(float x) {
    unsigned u = __float_as_uint(x);
    return (unsigned short)((u + 0x7FFFu + ((u >> 16) & 1u)) >> 16);  // RTNE
}
__device__ __forceinline__ float bf2f(unsigned short h) {
    return __uint_as_float(((unsigned)h) << 16);
}
__device__ __forceinline__ void g2lds16(const unsigned short* g, unsigned short* l) {
    __builtin_amdgcn_global_load_lds((uint_as1*)g, (uint_as3*)l, 16, 0, 0);
}

// ---------------------------------------------------------------------------
// mask int32 -> bitmask (1 bit per element), bit = laneId of each u64 word.
__global__ __launch_bounds__(256) void mask_pack(const int* __restrict__ m,
                                                 unsigned long long* __restrict__ out) {
    size_t i = (size_t)blockIdx.x * 256 + threadIdx.x;
    unsigned long long b = __ballot(m[i] != 0);
    if ((threadIdx.x & 63) == 0) out[i >> 6] = b;
}

// ---------------------------------------------------------------------------
// f32 -> bf16 hi/lo split for X [4096x1024] and W [1024x1024] (W scaled by wscale).
__global__ __launch_bounds__(256) void cvt_pair(
    const float* __restrict__ x, unsigned short* __restrict__ xh, unsigned short* __restrict__ xl,
    const float* __restrict__ w, unsigned short* __restrict__ wh, unsigned short* __restrict__ wl,
    float wscale) {
    const int NX4 = (B_ * S_ * D_) / 4;  // 1,048,576 float4s
    int i = blockIdx.x * 256 + threadIdx.x;
    const float* src;
    unsigned short* oh;
    unsigned short* ol;
    float sc;
    int off;
    if (i < NX4) { src = x; oh = xh; ol = xl; sc = 1.f; off = i; }
    else         { src = w; oh = wh; ol = wl; sc = wscale; off = i - NX4; }
    float4 f = ((const float4*)src)[off];
    float a0 = f.x * sc, a1 = f.y * sc, a2 = f.z * sc, a3 = f.w * sc;
    unsigned short h0 = f2bf(a0), h1 = f2bf(a1), h2 = f2bf(a2), h3 = f2bf(a3);
    u16x4 hv = {h0, h1, h2, h3};
    u16x4 lv = {f2bf(a0 - bf2f(h0)), f2bf(a1 - bf2f(h1)), f2bf(a2 - bf2f(h2)),
                f2bf(a3 - bf2f(h3))};
    *(u16x4*)(oh + (size_t)off * 4) = hv;
    *(u16x4*)(ol + (size_t)off * 4) = lv;
}

// ---------------------------------------------------------------------------
// out = X @ W^T + bias*bscale via split-bf16 MFMA (Xh*Wh + Xh*Wl + Xl*Wh).
// Pre-split bf16 inputs, staged with global_load_lds (width 16, linear LDS).
// BM=128, BN=64, BK=64, 256 thr (4 waves as 2x2, wave tile 64x32).
// VMODE==0: head-split hi/lo  out[(b*H+h)][s][hd]
// VMODE==1: tiled transpose   vt[(b*H+h)][s/64][hd(64)][s&63]  (bf16 hi only)
template <int VMODE>
__global__ __launch_bounds__(256) void proj_mfma(
    const unsigned short* __restrict__ Xh, const unsigned short* __restrict__ Xl,
    const unsigned short* __restrict__ Wh, const unsigned short* __restrict__ Wl,
    const float* __restrict__ bias, float bscale,
    unsigned short* __restrict__ o_hi, unsigned short* __restrict__ o_lo) {
    __shared__ __align__(16) unsigned short smem[24576];  // 48 KB
    unsigned short* Ah = smem;            // 128x64
    unsigned short* Al = smem + 8192;     // 128x64
    unsigned short* Bh = smem + 16384;    // 64x64
    unsigned short* Bl = smem + 20480;    // 64x64

    const int t = threadIdx.x;
    const int n0 = blockIdx.x * 64;
    const int m0 = blockIdx.y * 128;
    const int wid = t >> 6, l = t & 63;
    const int wm = wid >> 1, wn = wid & 1;
    const int lr = l & 15, lq = l >> 4;

    fx4 acc[4][2];
#pragma unroll
    for (int i = 0; i < 4; ++i)
#pragma unroll
        for (int j = 0; j < 2; ++j) acc[i][j] = (fx4){0.f, 0.f, 0.f, 0.f};

    for (int k0 = 0; k0 < D_; k0 += 64) {
#pragma unroll
        for (int j = 0; j < 4; ++j) {
            int u = t + j * 256;  // 0..1023 : 128 rows x 8 16B-units
            int row = u >> 3, cu = u & 7;
            size_t go = (size_t)(m0 + row) * D_ + k0 + cu * 8;
            g2lds16(Xh + go, Ah + u * 8);
            g2lds16(Xl + go, Al + u * 8);
        }
#pragma unroll
        for (int j = 0; j < 2; ++j) {
            int u = t + j * 256;  // 0..511 : 64 rows x 8 units
            int row = u >> 3, cu = u & 7;
            size_t go = (size_t)(n0 + row) * D_ + k0 + cu * 8;
            g2lds16(Wh + go, Bh + u * 8);
            g2lds16(Wl + go, Bl + u * 8);
        }
        __syncthreads();
#pragma unroll
        for (int c = 0; c < 2; ++c) {
            s16x8 a_h[4], a_l[4];
#pragma unroll
            for (int mf = 0; mf < 4; ++mf) {
                int ro = (wm * 64 + mf * 16 + lr) * 64 + c * 32 + lq * 8;
                a_h[mf] = *(const s16x8*)(Ah + ro);
                a_l[mf] = *(const s16x8*)(Al + ro);
            }
#pragma unroll
            for (int nf = 0; nf < 2; ++nf) {
                int ro = (wn * 32 + nf * 16 + lr) * 64 + c * 32 + lq * 8;
                s16x8 b_h = *(const s16x8*)(Bh + ro);
                s16x8 b_l = *(const s16x8*)(Bl + ro);
#pragma unroll
                for (int mf = 0; mf < 4; ++mf) {
                    acc[mf][nf] = MFMA16(a_h[mf], b_h, acc[mf][nf]);
                    acc[mf][nf] = MFMA16(a_h[mf], b_l, acc[mf][nf]);
                    acc[mf][nf] = MFMA16(a_l[mf], b_h, acc[mf][nf]);
                }
            }
        }
        __syncthreads();
    }

    if (VMODE == 0) {
#pragma unroll
        for (int nf = 0; nf < 2; ++nf) {
            int n = n0 + wn * 32 + nf * 16 + lr;
            float bv = bias[n] * bscale;
            int h = n >> 6, hd = n & 63;
#pragma unroll
            for (int mf = 0; mf < 4; ++mf)
#pragma unroll
                for (int r = 0; r < 4; ++r) {
                    int m = m0 + wm * 64 + mf * 16 + lq * 4 + r;
                    int b = m >> 11, s = m & 2047;
                    float v = acc[mf][nf][r] + bv;
                    size_t idx = ((size_t)((b * H_ + h) * S_ + s)) * HD_ + hd;
                    unsigned short hh = f2bf(v);
                    o_hi[idx] = hh;
                    o_lo[idx] = f2bf(v - bf2f(hh));
                }
        }
    } else {
        // transpose through LDS (reuse smem), then tiled vt writes
        unsigned short* T = smem;  // 64 x 136
#pragma unroll
        for (int nf = 0; nf < 2; ++nf) {
            int nl = wn * 32 + nf * 16 + lr;
            float bv = bias[n0 + nl] * bscale;
#pragma unroll
            for (int mf = 0; mf < 4; ++mf)
#pragma unroll
                for (int r = 0; r < 4; ++r) {
                    int ml = wm * 64 + mf * 16 + lq * 4 + r;
                    T[nl * 136 + ml] = f2bf(acc[mf][nf][r] + bv);
                }
        }
        __syncthreads();
        int h = n0 >> 6, b = m0 >> 11, s0 = m0 & 2047;
        int bhv = b * H_ + h;
        int hd = t >> 2, seg = t & 3;
        size_t vb0 = ((size_t)(bhv * 32 + (s0 >> 6) + (seg >> 1))) * 4096 +
                     (size_t)hd * 64 + (seg & 1) * 32;
#pragma unroll
        for (int j = 0; j < 4; ++j)
            *(u16x8*)(o_hi + vb0 + j * 8) = *(const u16x8*)(T + hd * 136 + seg * 32 + j * 8);
    }
}

// ---------------------------------------------------------------------------
// Fused attention, barrier-free. 4 waves/block, each wave owns 32 q-rows
// (two 16-row MFMA tiles); block = 128 q-rows. K/V fragments read directly
// from global (L2-resident); only per-wave LDS is the 32x72 bf16 P-buffer.
// Pass A: row-sums of exp (hi-only scores). Pass B: hi/lo scores, write
// normalized attn from regs, bf16-P PV MFMA.
__global__ __launch_bounds__(256) void attn_mfma(
    const unsigned short* __restrict__ qh_g, const unsigned short* __restrict__ ql_g,
    const unsigned short* __restrict__ kh_g, const unsigned short* __restrict__ kl_g,
    const unsigned short* __restrict__ vt_g, const unsigned long long* __restrict__ pm,
    float* __restrict__ out_ctx, float* __restrict__ out_attn) {
    __shared__ __align__(16) unsigned short Ew[4 * 32 * 72];  // per-wave P bf16

    const int t = threadIdx.x;
    const int wid = t >> 6, l = t & 63, lr = l & 15, lq = l >> 4;
    const int q0 = blockIdx.x * 128;
    const int bh = blockIdx.y;
    const size_t base = (size_t)bh * S_ * HD_;
    const int qr = q0 + wid * 32;
    const size_t mrow0 = (size_t)(bh & (B_ - 1)) * S_ + qr;  // faithful: mask[bh % B]
    unsigned short* ew = Ew + wid * 32 * 72;

    // Q fragments: row = qr + mt*16 + lr, k = c*32 + lq*8 .. +8
    s16x8 qhi[2][2], qlo[2][2];
#pragma unroll
    for (int mt = 0; mt < 2; ++mt) {
        const unsigned short* qp = qh_g + base + (size_t)(qr + mt * 16 + lr) * HD_ + lq * 8;
        qhi[mt][0] = *(const s16x8*)qp;
        qhi[mt][1] = *(const s16x8*)(qp + 32);
        const unsigned short* qp2 = ql_g + base + (size_t)(qr + mt * 16 + lr) * HD_ + lq * 8;
        qlo[mt][0] = *(const s16x8*)qp2;
        qlo[mt][1] = *(const s16x8*)(qp2 + 32);
    }

    float rs[2][4] = {};

    // ---------------- pass A: row sums of exp ----------------
    for (int kt = 0; kt < S_; kt += 64) {
        const unsigned short* kp = kh_g + base + (size_t)(kt + lr) * HD_ + lq * 8;
        fx4 acc[2][4];
#pragma unroll
        for (int mt = 0; mt < 2; ++mt)
#pragma unroll
            for (int nt = 0; nt < 4; ++nt) acc[mt][nt] = (fx4){0.f, 0.f, 0.f, 0.f};
#pragma unroll
        for (int c = 0; c < 2; ++c)
#pragma unroll
            for (int nt = 0; nt < 4; ++nt) {
                s16x8 kb = *(const s16x8*)(kp + nt * 16 * HD_ + c * 32);
                acc[0][nt] = MFMA16(qhi[0][c], kb, acc[0][nt]);
                acc[1][nt] = MFMA16(qhi[1][c], kb, acc[1][nt]);
            }
#pragma unroll
        for (int mt = 0; mt < 2; ++mt) {
            unsigned long long mw[4];
#pragma unroll
            for (int r = 0; r < 4; ++r)
                mw[r] = pm[(mrow0 + mt * 16 + lq * 4 + r) * (S_ / 64) + (kt >> 6)];
#pragma unroll
            for (int nt = 0; nt < 4; ++nt)
#pragma unroll
                for (int r = 0; r < 4; ++r) {
                    float e = EXP2F(acc[mt][nt][r]);
                    e = ((mw[r] >> (nt * 16 + lr)) & 1ull) ? 0.f : e;
                    rs[mt][r] += e;
                }
        }
    }
#pragma unroll
    for (int off = 1; off < 16; off <<= 1)
#pragma unroll
        for (int mt = 0; mt < 2; ++mt)
#pragma unroll
            for (int r = 0; r < 4; ++r) rs[mt][r] += __shfl_xor(rs[mt][r], off, 16);
    float inv[2][4];
#pragma unroll
    for (int mt = 0; mt < 2; ++mt)
#pragma unroll
        for (int r = 0; r < 4; ++r) inv[mt][r] = 1.f / rs[mt][r];

    // ---------------- pass B: normalized attn + PV ----------------
    fx4 pacc[2][4];
#pragma unroll
    for (int mt = 0; mt < 2; ++mt)
#pragma unroll
        for (int dt = 0; dt < 4; ++dt) pacc[mt][dt] = (fx4){0.f, 0.f, 0.f, 0.f};

    for (int kt = 0; kt < S_; kt += 64) {
        const unsigned short* kph = kh_g + base + (size_t)(kt + lr) * HD_ + lq * 8;
        const unsigned short* kpl = kl_g + base + (size_t)(kt + lr) * HD_ + lq * 8;
        fx4 acc[2][4];
#pragma unroll
        for (int mt = 0; mt < 2; ++mt)
#pragma unroll
            for (int nt = 0; nt < 4; ++nt) acc[mt][nt] = (fx4){0.f, 0.f, 0.f, 0.f};
#pragma unroll
        for (int c = 0; c < 2; ++c)
#pragma unroll
            for (int nt = 0; nt < 4; ++nt) {
                s16x8 kbh = *(const s16x8*)(kph + nt * 16 * HD_ + c * 32);
                s16x8 kbl = *(const s16x8*)(kpl + nt * 16 * HD_ + c * 32);
#pragma unroll
                for (int mt = 0; mt < 2; ++mt) {
                    acc[mt][nt] = MFMA16(qhi[mt][c], kbh, acc[mt][nt]);
                    acc[mt][nt] = MFMA16(qhi[mt][c], kbl, acc[mt][nt]);
                    acc[mt][nt] = MFMA16(qlo[mt][c], kbh, acc[mt][nt]);
                }
            }
#pragma unroll
        for (int mt = 0; mt < 2; ++mt) {
            unsigned long long mw[4];
#pragma unroll
            for (int r = 0; r < 4; ++r)
                mw[r] = pm[(mrow0 + mt * 16 + lq * 4 + r) * (S_ / 64) + (kt >> 6)];
            float* ap = out_attn + ((size_t)bh * S_ + qr + mt * 16 + lq * 4) * S_ + kt + lr;
#pragma unroll
            for (int nt = 0; nt < 4; ++nt)
#pragma unroll
                for (int r = 0; r < 4; ++r) {
                    float e = EXP2F(acc[mt][nt][r]);
                    e = ((mw[r] >> (nt * 16 + lr)) & 1ull) ? 0.f : e * inv[mt][r];
                    ap[(size_t)r * S_ + nt * 16] = e;
                    ew[(mt * 16 + lq * 4 + r) * 72 + nt * 16 + lr] = f2bf(e);
                }
        }
        __builtin_amdgcn_wave_barrier();
        // PV: A = P rows (lr within m-tile), B = V^T tiled [ktile][d][k64]
        const unsigned short* vp = vt_g + ((size_t)(bh * 32 + (kt >> 6))) * 4096;
#pragma unroll
        for (int c = 0; c < 2; ++c) {
            s16x8 pa0 = *(const s16x8*)(ew + lr * 72 + c * 32 + lq * 8);
            s16x8 pa1 = *(const s16x8*)(ew + (16 + lr) * 72 + c * 32 + lq * 8);
#pragma unroll
            for (int dt = 0; dt < 4; ++dt) {
                s16x8 vb = *(const s16x8*)(vp + (dt * 16 + lr) * 64 + c * 32 + lq * 8);
                pacc[0][dt] = MFMA16(pa0, vb, pacc[0][dt]);
                pacc[1][dt] = MFMA16(pa1, vb, pacc[1][dt]);
            }
        }
        __builtin_amdgcn_wave_barrier();
    }

    // ctx epilogue: D layout row=(lane>>4)*4+reg (q), col=lane&15 (d)
    const int b = bh >> 4, h = bh & 15;
#pragma unroll
    for (int mt = 0; mt < 2; ++mt)
#pragma unroll
        for (int dt = 0; dt < 4; ++dt)
#pragma unroll
            for (int r = 0; r < 4; ++r) {
                int q = qr + mt * 16 + lq * 4 + r;
                out_ctx[((size_t)(b * S_ + q)) * D_ + h * HD_ + dt * 16 + lr] =
                    pacc[mt][dt][r];
            }
}

// ---------------------------------------------------------------------------
extern "C" void kernel_launch(void* const* d_in, const int* in_sizes, int n_in,
                              void* d_out, int out_size, void* d_ws, size_t ws_size,
                              hipStream_t stream) {
    (void)in_sizes; (void)n_in; (void)out_size; (void)ws_size;
    const float* q_in = (const float*)d_in[0];
    const float* k_in = (const float*)d_in[1];
    const float* v_in = (const float*)d_in[2];
    const int* mask = (const int*)d_in[3];
    const float* Wq = (const float*)d_in[4];
    const float* bq = (const float*)d_in[5];
    const float* Wk = (const float*)d_in[6];
    const float* bk = (const float*)d_in[7];
    const float* Wv = (const float*)d_in[8];
    const float* bv = (const float*)d_in[9];

    const size_t E_ = (size_t)BH_ * S_ * HD_;  // 4,194,304
    const size_t WE_ = (size_t)D_ * D_;        // 1,048,576
    unsigned short* qh = (unsigned short*)d_ws;
    unsigned short* ql = qh + E_;
    unsigned short* kh = ql + E_;
    unsigned short* kl = kh + E_;
    unsigned short* vt = kl + E_;
    unsigned short* Xh = vt + E_;
    unsigned short* Xl = Xh + E_;
    unsigned short* Wh = Xl + E_;
    unsigned short* Wl = Wh + WE_;
    unsigned long long* pmask = (unsigned long long*)(Wl + WE_);
    // total ws: 7*8MB + 2*2MB + 1MB = ~61MB

    float* ctx = (float*)d_out;
    float* attn = ctx + (size_t)B_ * S_ * D_;

    mask_pack<<<dim3((B_ * S_ * S_) / 256), dim3(256), 0, stream>>>(mask, pmask);

    const int CG = ((B_ * S_ * D_) / 4 + (D_ * D_) / 4) / 256;  // 5120
    dim3 pgrid(D_ / 64, (B_ * S_) / 128);                       // (16, 32)

    cvt_pair<<<dim3(CG), dim3(256), 0, stream>>>(q_in, Xh, Xl, Wq, Wh, Wl, QSCALE);
    proj_mfma<0><<<pgrid, dim3(256), 0, stream>>>(Xh, Xl, Wh, Wl, bq, QSCALE, qh, ql);

    cvt_pair<<<dim3(CG), dim3(256), 0, stream>>>(k_in, Xh, Xl, Wk, Wh, Wl, 1.0f);
    proj_mfma<0><<<pgrid, dim3(256), 0, stream>>>(Xh, Xl, Wh, Wl, bk, 1.0f, kh, kl);

    cvt_pair<<<dim3(CG), dim3(256), 0, stream>>>(v_in, Xh, Xl, Wv, Wh, Wl, 1.0f);
    proj_mfma<1><<<pgrid, dim3(256), 0, stream>>>(Xh, Xl, Wh, Wl, bv, 1.0f, vt, nullptr);

    dim3 agrid(S_ / 128, BH_);  // (16, 32)
    attn_mfma<<<agrid, dim3(256), 0, stream>>>(qh, ql, kh, kl, vt, pmask, ctx, attn);
}